// Round 11
// baseline (91.009 us; speedup 1.0000x reference)
//
#include <hip/hip_runtime.h>

// ---------------------------------------------------------------------------
// KAN forward as one bf16 MFMA GEMM:
//   y[n,o] = sum_i ( silu(x[n,i])*scale_base[o,i]
//                  + sum_b basis_b(x[n,i]) * scale_sp[o,i]*coef[o,i,b] ) + bias[o]
// A[n, i*8+s], W[o, i*8+s]: s=0 -> (silu, scale_base); s=1..6 -> (basis, sp*coef);
// s=7 -> zero pad.  K = 512*8 = 4096.
// Round 11: BN=512 -> each block covers ALL outputs for its 64 rows, so
// activations are computed exactly once chip-wide (was 2x): VALU pipe halves.
// 512 threads = 8 waves 1Mx8N, wave tile 64x64 (per-wave structure identical
// to r10's proven core). B direct from L2 (single 4MB packed W, all blocks
// walk kt together -> live window ~32KB), A-LDS dbuf, register-built act,
// one ds_write_b128, setprio around MFMA.
// ---------------------------------------------------------------------------

typedef short        bf16x8 __attribute__((ext_vector_type(8)));
typedef float        f32x4  __attribute__((ext_vector_type(4)));
typedef unsigned int u32x4  __attribute__((ext_vector_type(4)));

#define NROWS 16384
#define DIN   512
#define DOUT  512
#define BM    64
#define BN    512
#define NKT   64              // K-steps; each covers 8 input features (64 k-units)

__device__ __forceinline__ unsigned short f2bf(float f) {
    unsigned int u = __float_as_uint(f);
    u += 0x7fffu + ((u >> 16) & 1u);          // round-to-nearest-even
    return (unsigned short)(u >> 16);
}

// ---------------------------------------------------------------------------
// Register-built activation: 8 bf16 slots [silu, basis0..5, pad] for one x.
// Cell-local: S = 1.5x+4.5, j = floor(S), t = S-j; cardinal cubics n0..n3 land
// at slots j-2..j+1 (slot = basis index + 1). Placement done in registers:
//   even j: words (P01,P23) at word-base b=(j-2)>>1
//   odd  j: words (U,V,Z)   at word-base b          (16-bit-shifted variants)
// slot0 always overwritten by silu (absorbs the b=-1 clip); slot7 spillover is
// harmless (W pad = 0); out-of-range j -> all-zero. Single ds_write_b128.
// ---------------------------------------------------------------------------
__device__ __forceinline__ void kan_act_store(float xv, char* p16) {
    float S  = __builtin_fmaf(xv, 1.5f, 4.5f);
    float jf = floorf(S);
    float t  = S - jf;
    int   j  = (int)jf;
    float t2 = t * t;
    float t3 = t2 * t;
    float omt  = 1.0f - t;
    float omt2 = omt * omt;
    float n0 = omt2 * omt * (1.0f / 6.0f);                    // (1-t)^3/6
    float n1 = __builtin_fmaf(t3, 0.5f, -t2) + (2.0f / 3.0f); // (3t^3-6t^2+4)/6
    float u  = (t + t2) - t3;
    float n2 = __builtin_fmaf(u, 0.5f, 1.0f / 6.0f);          // (-3t^3+3t^2+3t+1)/6
    float n3 = t3 * (1.0f / 6.0f);                            // t^3/6
    float e  = __expf(-xv);
    float si = xv * __builtin_amdgcn_rcpf(1.0f + e);          // silu

    unsigned P01, P23, WS;
    asm("v_cvt_pk_bf16_f32 %0, %1, %2" : "=v"(P01) : "v"(n0), "v"(n1));
    asm("v_cvt_pk_bf16_f32 %0, %1, %2" : "=v"(P23) : "v"(n2), "v"(n3));
    asm("v_cvt_pk_bf16_f32 %0, %1, %2" : "=v"(WS)  : "v"(si), "v"(0.0f));
    unsigned U = P01 << 16;                      // (0 , n0)
    unsigned V = (P01 >> 16) | (P23 << 16);      // (n1, n2)
    unsigned Z = P23 >> 16;                      // (n3, 0 )
    bool odd = (j & 1) != 0;
    unsigned c0 = odd ? U : P01;
    unsigned c1 = odd ? V : P23;
    unsigned c2 = odd ? Z : 0u;
    int b = (j - 2) >> 1;                        // arithmetic shift (floor)
    u32x4 w;
    w[0] = (b == 0) ? c0 : (b == -1) ? c1 : (b == -2) ? c2 : 0u;
    w[1] = (b == 1) ? c0 : (b ==  0) ? c1 : (b == -1) ? c2 : 0u;
    w[2] = (b == 2) ? c0 : (b ==  1) ? c1 : (b ==  0) ? c2 : 0u;
    w[3] = (b == 3) ? c0 : (b ==  2) ? c1 : (b ==  1) ? c2 : 0u;
    w[0] = (w[0] & 0xFFFF0000u) | (WS & 0xFFFFu);   // silu -> slot 0
    *(u32x4*)p16 = w;
}

// ---------------------------------------------------------------------------
// Prep: pack W into ws as bf16 16B slot-groups, laid out so GEMM B-frag wave
// loads are contiguous:
//   byte = ((kt*2 + ks)*512 + o)*64 + fg*16
// where i = kt*8 + ks*4 + fg.  One 4MB region; per (kt,ks) slice = 32 KB.
// ---------------------------------------------------------------------------
__global__ __launch_bounds__(256) void kan_prep(
    const float* __restrict__ coef, const float* __restrict__ scale_base,
    const float* __restrict__ scale_sp, unsigned short* __restrict__ wt)
{
    int t = blockIdx.x * 256 + threadIdx.x;   // t = o*512 + i
    int o = t >> 9;
    int i = t & 511;
    float sb = scale_base[t];
    float sp = scale_sp[t];
    const float* cp = coef + (size_t)t * 6;
    bf16x8 w;
    w[0] = (short)f2bf(sb);
#pragma unroll
    for (int b = 0; b < 6; ++b) w[1 + b] = (short)f2bf(sp * cp[b]);
    w[7] = 0;
    int kt = i >> 3, s = i & 7, ks = s >> 2, fg = s & 3;
    size_t off = ((size_t)((kt * 2 + ks) * 512 + o)) * 64 + fg * 16;
    *(bf16x8*)((char*)wt + off) = w;
}

// ---------------------------------------------------------------------------
// Fused GEMM: BM=64 x BN=512, BK=64 (8 features), 512 threads (8 waves 1Mx8N,
// wave tile 64x64 = 4x4 frags of 16x16x32). A in LDS dbuf (16KB); B global->reg.
// grid 256 = 1 block/CU; acts computed once chip-wide.
// ---------------------------------------------------------------------------
__global__ __launch_bounds__(512, 2) void kan_gemm(
    const float* __restrict__ x, const unsigned short* __restrict__ wt,
    const float* __restrict__ bias, float* __restrict__ y)
{
    __shared__ char As[2][BM * 128];   // 2 x 8 KB, swizzled rows of 64 bf16

    const int tid  = threadIdx.x;
    const int lane = tid & 63;
    const int wid  = tid >> 6;        // 0..7 (= wn, 64-col slice)

    // bijective XCD-aware swizzle: 256 wgs, 8 XCDs, contiguous 32-chunk each.
    int bid = blockIdx.x;
    int mt  = (bid & 7) * 32 + (bid >> 3);    // 0..255

    const int row0 = mt * BM;

    // A staging: thread -> (row ar, feature ap); ONE act per thread per step
    const int ar = tid >> 3;          // 0..63
    const int ap = tid & 7;           // 0..7
    const float* xp = x + (size_t)(row0 + ar) * DIN + ap;
    const int as_sw = (ar & 7) << 4;
    const int c0 = ap << 4;
    char* const arow0 = &As[0][ar * 128];
    char* const arow1 = &As[1][ar * 128];

    const int fr = lane & 15;         // fragment row/col
    const int fg = lane >> 4;         // k-group 0..3

    // B-frag bases: frag (ks, n2) at iter kt reads 16B from
    //   wt + (kt*2+ks)*32768 + colpart[n2],  colpart = (wid*64+n2*16+fr)*64 + fg*16
    // -> wave's 64 lanes (fr,fg) cover 1024 contiguous bytes (coalesced).
    const char* wb = (const char*)wt;
    int colpart[4];
#pragma unroll
    for (int n2 = 0; n2 < 4; ++n2)
        colpart[n2] = (wid * 64 + n2 * 16 + fr) * 64 + fg * 16;

#define LOADB(B, ktv)                                                         \
    {                                                                         \
        _Pragma("unroll")                                                     \
        for (int q = 0; q < 8; ++q) {                                         \
            int n2_ = q & 3, ks_ = q >> 2;                                    \
            B[q] = *(const bf16x8*)(wb + (size_t)((ktv) * 2 + ks_) * 32768    \
                                    + colpart[n2_]);                          \
        }                                                                     \
    }

    f32x4 acc[4][4];
#pragma unroll
    for (int m2 = 0; m2 < 4; ++m2)
#pragma unroll
        for (int n2 = 0; n2 < 4; ++n2) {
            f32x4 z = {0.f, 0.f, 0.f, 0.f};
            acc[m2][n2] = z;
        }

    bf16x8 Ba[8], Bb[8];

    // ---------------- prologue: B(0) -> Ba, act(0) -> As[0] ----------------
    LOADB(Ba, 0);
    kan_act_store(xp[0], arow0 + (c0 ^ as_sw));
    float xb = xp[8];                 // x for kt=1
    asm volatile("s_waitcnt lgkmcnt(0)" ::: "memory");
    __builtin_amdgcn_s_barrier();

// one K-step: consume Bcur + As[ktv&1]; produce Bnext + As[(ktv+1)&1].
// A-frag ds_reads issued first (latency hides under act VALU); MFMA's use of
// Bcur gets a compiler-counted vmcnt (Bnext's 8 loads stay in flight).
#define STEP(ktv, Bcur, Bnext)                                                \
    {                                                                         \
        const int cur_ = (ktv) & 1;                                           \
        bf16x8 af_[2][4];                                                     \
        _Pragma("unroll")                                                     \
        for (int ks_ = 0; ks_ < 2; ++ks_) {                                   \
            _Pragma("unroll")                                                 \
            for (int m2_ = 0; m2_ < 4; ++m2_) {                               \
                int rr_ = m2_ * 16 + fr;                                      \
                af_[ks_][m2_] = *(const bf16x8*)(&As[cur_][0] + rr_ * 128     \
                    + ((ks_ * 64 + fg * 16) ^ ((rr_ & 7) << 4)));             \
            }                                                                 \
        }                                                                     \
        if ((ktv) + 1 < NKT) {                                                \
            LOADB(Bnext, (ktv) + 1);                                          \
            char* rowp_ = (((ktv) + 1) & 1) ? arow1 : arow0;                  \
            kan_act_store(xb, rowp_ + (c0 ^ as_sw));                          \
            if ((ktv) + 2 < NKT) xb = xp[((ktv) + 2) * 8];                    \
        }                                                                     \
        __builtin_amdgcn_s_setprio(1);                                        \
        _Pragma("unroll")                                                     \
        for (int ks_ = 0; ks_ < 2; ++ks_)                                     \
            _Pragma("unroll")                                                 \
            for (int m2_ = 0; m2_ < 4; ++m2_)                                 \
                _Pragma("unroll")                                             \
                for (int n2_ = 0; n2_ < 4; ++n2_)                             \
                    acc[m2_][n2_] = __builtin_amdgcn_mfma_f32_16x16x32_bf16(  \
                        af_[ks_][m2_], Bcur[ks_ * 4 + n2_], acc[m2_][n2_],    \
                        0, 0, 0);                                             \
        __builtin_amdgcn_s_setprio(0);                                        \
        asm volatile("s_waitcnt lgkmcnt(0)" ::: "memory");                    \
        __builtin_amdgcn_s_barrier();                                         \
    }

    for (int kt = 0; kt < NKT; kt += 2) {
        STEP(kt, Ba, Bb);
        STEP(kt + 1, Bb, Ba);
    }

    // ---- epilogue: C/D layout col = lane&15, row = (lane>>4)*4 + reg
    const int orow0 = row0 + fg * 4;
    const int ocol0 = wid * 64 + fr;
#pragma unroll
    for (int n2 = 0; n2 < 4; ++n2) {
        float bv = bias[ocol0 + n2 * 16];
#pragma unroll
        for (int m2 = 0; m2 < 4; ++m2) {
#pragma unroll
            for (int r = 0; r < 4; ++r) {
                y[(size_t)(orow0 + m2 * 16 + r) * DOUT + (ocol0 + n2 * 16)]
                    = acc[m2][n2][r] + bv;
            }
        }
    }
#undef STEP
#undef LOADB
}

extern "C" void kernel_launch(void* const* d_in, const int* in_sizes, int n_in,
                              void* d_out, int out_size, void* d_ws, size_t ws_size,
                              hipStream_t stream)
{
    const float* x          = (const float*)d_in[0];
    const float* coef       = (const float*)d_in[1];
    const float* scale_base = (const float*)d_in[2];
    const float* scale_sp   = (const float*)d_in[3];
    const float* bias       = (const float*)d_in[4];
    unsigned short* wt = (unsigned short*)d_ws;   // 4 MB packed wt[kt][ks][o][fg]
    float* y = (float*)d_out;

    kan_prep<<<1024, 256, 0, stream>>>(coef, scale_base, scale_sp, wt);
    kan_gemm<<<256, 512, 0, stream>>>(x, wt, bias, y);
}

// Round 12
// 81.363 us; speedup vs baseline: 1.1186x; 1.1186x over previous
//
#include <hip/hip_runtime.h>

// ---------------------------------------------------------------------------
// KAN forward as one bf16 MFMA GEMM:
//   y[n,o] = sum_i ( silu(x[n,i])*scale_base[o,i]
//                  + sum_b basis_b(x[n,i]) * scale_sp[o,i]*coef[o,i,b] ) + bias[o]
// A[n, i*8+s], W[o, i*8+s]: s=0 -> (silu, scale_base); s=1..6 -> (basis, sp*coef);
// s=7 -> zero pad.  K = 512*8 = 4096.
// Round 12: r10 core (BM=64/BN=256, 4 waves, 2 blocks/CU, B->regs dbuf,
// register-built acts) with SUPERSTEP restructure: 4 kt per barrier instead of
// 1. LDS = 2 rings x 4 substep-buffers x 8KB; substeps read ring[cur], acts
// for the NEXT superstep write ring[cur^1] -> no barrier needed inside a
// superstep. Barriers 64 -> 16; waves/blocks drift up to 4 kt -> wave-phase
// diversity lets the CU co-issue act-VALU with MFMA (m114).
// ---------------------------------------------------------------------------

typedef short        bf16x8 __attribute__((ext_vector_type(8)));
typedef float        f32x4  __attribute__((ext_vector_type(4)));
typedef unsigned int u32x4  __attribute__((ext_vector_type(4)));

#define NROWS 16384
#define DIN   512
#define DOUT  512
#define BM    64
#define BN    256
#define NKT   64              // K-steps; each covers 8 input features
#define NSS   16              // supersteps of 4 kt

__device__ __forceinline__ unsigned short f2bf(float f) {
    unsigned int u = __float_as_uint(f);
    u += 0x7fffu + ((u >> 16) & 1u);          // round-to-nearest-even
    return (unsigned short)(u >> 16);
}

// ---------------------------------------------------------------------------
// Register-built activation: 8 bf16 slots [silu, basis0..5, pad] for one x.
// Cell-local: S = 1.5x+4.5, j = floor(S), t = S-j; cardinal cubics n0..n3 land
// at slots j-2..j+1. Placement in registers (parity + word-base cndmask),
// silu bfi'd into slot 0, one ds_write_b128. Out-of-range -> zeros / pad slot.
// ---------------------------------------------------------------------------
__device__ __forceinline__ void kan_act_store(float xv, char* p16) {
    float S  = __builtin_fmaf(xv, 1.5f, 4.5f);
    float jf = floorf(S);
    float t  = S - jf;
    int   j  = (int)jf;
    float t2 = t * t;
    float t3 = t2 * t;
    float omt  = 1.0f - t;
    float omt2 = omt * omt;
    float n0 = omt2 * omt * (1.0f / 6.0f);                    // (1-t)^3/6
    float n1 = __builtin_fmaf(t3, 0.5f, -t2) + (2.0f / 3.0f); // (3t^3-6t^2+4)/6
    float u  = (t + t2) - t3;
    float n2 = __builtin_fmaf(u, 0.5f, 1.0f / 6.0f);          // (-3t^3+3t^2+3t+1)/6
    float n3 = t3 * (1.0f / 6.0f);                            // t^3/6
    float e  = __expf(-xv);
    float si = xv * __builtin_amdgcn_rcpf(1.0f + e);          // silu

    unsigned P01, P23, WS;
    asm("v_cvt_pk_bf16_f32 %0, %1, %2" : "=v"(P01) : "v"(n0), "v"(n1));
    asm("v_cvt_pk_bf16_f32 %0, %1, %2" : "=v"(P23) : "v"(n2), "v"(n3));
    asm("v_cvt_pk_bf16_f32 %0, %1, %2" : "=v"(WS)  : "v"(si), "v"(0.0f));
    unsigned U = P01 << 16;                      // (0 , n0)
    unsigned V = (P01 >> 16) | (P23 << 16);      // (n1, n2)
    unsigned Z = P23 >> 16;                      // (n3, 0 )
    bool odd = (j & 1) != 0;
    unsigned c0 = odd ? U : P01;
    unsigned c1 = odd ? V : P23;
    unsigned c2 = odd ? Z : 0u;
    int b = (j - 2) >> 1;                        // arithmetic shift (floor)
    u32x4 w;
    w[0] = (b == 0) ? c0 : (b == -1) ? c1 : (b == -2) ? c2 : 0u;
    w[1] = (b == 1) ? c0 : (b ==  0) ? c1 : (b == -1) ? c2 : 0u;
    w[2] = (b == 2) ? c0 : (b ==  1) ? c1 : (b ==  0) ? c2 : 0u;
    w[3] = (b == 3) ? c0 : (b ==  2) ? c1 : (b ==  1) ? c2 : 0u;
    w[0] = (w[0] & 0xFFFF0000u) | (WS & 0xFFFFu);   // silu -> slot 0
    *(u32x4*)p16 = w;
}

// ---------------------------------------------------------------------------
// Prep: pack W into ws as bf16 16B slot-groups, coalesced for the GEMM:
//   byte = nt*2MB + ((kt*2 + ks)*256 + ol)*64 + fg*16
// where o = nt*256+ol, i = kt*8 + ks*4 + fg.
// ---------------------------------------------------------------------------
__global__ __launch_bounds__(256) void kan_prep(
    const float* __restrict__ coef, const float* __restrict__ scale_base,
    const float* __restrict__ scale_sp, unsigned short* __restrict__ wt)
{
    int t = blockIdx.x * 256 + threadIdx.x;   // t = o*512 + i
    int o = t >> 9;
    int i = t & 511;
    float sb = scale_base[t];
    float sp = scale_sp[t];
    const float* cp = coef + (size_t)t * 6;
    bf16x8 w;
    w[0] = (short)f2bf(sb);
#pragma unroll
    for (int b = 0; b < 6; ++b) w[1 + b] = (short)f2bf(sp * cp[b]);
    w[7] = 0;
    int nt = o >> 8, ol = o & 255;
    int kt = i >> 3, s = i & 7, ks = s >> 2, fg = s & 3;
    size_t off = (size_t)nt * 2097152
               + (size_t)((kt * 2 + ks) * 256 + ol) * 64 + fg * 16;
    *(bf16x8*)((char*)wt + off) = w;
}

// ---------------------------------------------------------------------------
// Fused GEMM: BM=64 x BN=256, 256 threads (4 waves, wave tile 64x64), B from
// L2 to regs (dbuf), A in LDS superstep rings. 1 barrier per 4 kt.
// ---------------------------------------------------------------------------
__global__ __launch_bounds__(256, 2) void kan_gemm(
    const float* __restrict__ x, const unsigned short* __restrict__ wt,
    const float* __restrict__ bias, float* __restrict__ y)
{
    __shared__ char As[2][4][BM * 128];   // 2 rings x 4 substeps x 8KB = 64KB

    const int tid  = threadIdx.x;
    const int lane = tid & 63;
    const int wid  = tid >> 6;        // 0..3 (= wn)

    // bijective XCD-aware swizzle: 512 wgs, 8 XCDs, contiguous 64-chunk each.
    int bid = blockIdx.x;
    int wg  = (bid & 7) * 64 + (bid >> 3);
    int mt  = wg & 255;
    int nt  = wg >> 8;

    const int row0 = mt * BM;
    const int col0 = nt * BN;

    // A staging: thread -> (row ar, feature-pair ap)
    const int ar = tid >> 2;          // 0..63
    const int ap = tid & 3;           // 0..3
    const float* xp = x + (size_t)(row0 + ar) * DIN + ap * 2;
    const int as_sw = (ar & 7) << 4;
    const int c0 = (ap * 2) << 4;

    const int fr = lane & 15;         // fragment row/col
    const int fg = lane >> 4;         // k-group 0..3

    // B-frag bases (coalesced wt2 layout, r7-proven)
    const char* wb = (const char*)wt + (size_t)nt * 2097152;
    int colpart[4];
#pragma unroll
    for (int n2 = 0; n2 < 4; ++n2)
        colpart[n2] = (wid * 64 + n2 * 16 + fr) * 64 + fg * 16;

#define LOADB(B, ktv)                                                         \
    {                                                                         \
        _Pragma("unroll")                                                     \
        for (int q = 0; q < 8; ++q) {                                         \
            int n2_ = q & 3, ks_ = q >> 2;                                    \
            B[q] = *(const bf16x8*)(wb + (size_t)((ktv) * 2 + ks_) * 16384    \
                                    + colpart[n2_]);                          \
        }                                                                     \
    }

    f32x4 acc[4][4];
#pragma unroll
    for (int m2 = 0; m2 < 4; ++m2)
#pragma unroll
        for (int n2 = 0; n2 < 4; ++n2) {
            f32x4 z = {0.f, 0.f, 0.f, 0.f};
            acc[m2][n2] = z;
        }

    bf16x8 Ba[8], Bb[8];

    // ---------------- prologue: acts(kt 0..3) -> ring0, B(0) -> Ba ----------
    LOADB(Ba, 0);
#pragma unroll
    for (int j = 0; j < 4; ++j) {
        float2 xa = *(const float2*)(xp + j * 8);
        char* rowp = &As[0][j][ar * 128];
        kan_act_store(xa.x, rowp + (c0 ^ as_sw));
        kan_act_store(xa.y, rowp + ((c0 + 16) ^ as_sw));
    }
    // x prefetch for superstep 1 (kts 4..7)
    float2 xq0 = *(const float2*)(xp + 4 * 8);
    float2 xq1 = *(const float2*)(xp + 5 * 8);
    float2 xq2 = *(const float2*)(xp + 6 * 8);
    float2 xq3 = *(const float2*)(xp + 7 * 8);
    asm volatile("s_waitcnt lgkmcnt(0)" ::: "memory");
    __builtin_amdgcn_s_barrier();

// one substep (kt = ss*4+jc): ds_read A-frags from ring[cur][jc]; issue
// B(kt+1) into Bnext (used next substep; acts+MFMA cover the latency); acts
// for kt' = (ss+1)*4+jc -> ring[cur^1][jc] (no barrier needed: other ring);
// 32 MFMA on (af, Bcur). No barrier here - waves drift within the superstep.
#define SUBSTEP(jc, Bcur, Bnext, xq)                                          \
    {                                                                         \
        const int kt_ = ss * 4 + (jc);                                        \
        const int cur_ = ss & 1;                                              \
        bf16x8 af_[2][4];                                                     \
        _Pragma("unroll")                                                     \
        for (int ks_ = 0; ks_ < 2; ++ks_) {                                   \
            _Pragma("unroll")                                                 \
            for (int m2_ = 0; m2_ < 4; ++m2_) {                               \
                int rr_ = m2_ * 16 + fr;                                      \
                af_[ks_][m2_] = *(const bf16x8*)(&As[cur_][jc][0] + rr_ * 128 \
                    + ((ks_ * 64 + fg * 16) ^ ((rr_ & 7) << 4)));             \
            }                                                                 \
        }                                                                     \
        if (kt_ + 1 < NKT) LOADB(Bnext, kt_ + 1);                             \
        if (ss + 1 < NSS) {                                                   \
            char* rowp_ = &As[cur_ ^ 1][jc][ar * 128];                        \
            kan_act_store(xq.x, rowp_ + (c0 ^ as_sw));                        \
            kan_act_store(xq.y, rowp_ + ((c0 + 16) ^ as_sw));                 \
            if (ss + 2 < NSS)                                                 \
                xq = *(const float2*)(xp + ((ss + 2) * 4 + (jc)) * 8);        \
        }                                                                     \
        __builtin_amdgcn_s_setprio(1);                                        \
        _Pragma("unroll")                                                     \
        for (int ks_ = 0; ks_ < 2; ++ks_)                                     \
            _Pragma("unroll")                                                 \
            for (int m2_ = 0; m2_ < 4; ++m2_)                                 \
                _Pragma("unroll")                                             \
                for (int n2_ = 0; n2_ < 4; ++n2_)                             \
                    acc[m2_][n2_] = __builtin_amdgcn_mfma_f32_16x16x32_bf16(  \
                        af_[ks_][m2_], Bcur[ks_ * 4 + n2_], acc[m2_][n2_],    \
                        0, 0, 0);                                             \
        __builtin_amdgcn_s_setprio(0);                                        \
    }

    for (int ss = 0; ss < NSS; ++ss) {
        SUBSTEP(0, Ba, Bb, xq0);
        SUBSTEP(1, Bb, Ba, xq1);
        SUBSTEP(2, Ba, Bb, xq2);
        SUBSTEP(3, Bb, Ba, xq3);
        // one barrier per superstep: ring[cur^1] fully written (lgkmcnt
        // drains the ds_writes) and ring[cur] fully consumed before reuse.
        asm volatile("s_waitcnt lgkmcnt(0)" ::: "memory");
        __builtin_amdgcn_s_barrier();
    }

    // ---- epilogue: C/D layout col = lane&15, row = (lane>>4)*4 + reg
    const int orow0 = row0 + fg * 4;
    const int ocol0 = col0 + wid * 64 + fr;
#pragma unroll
    for (int n2 = 0; n2 < 4; ++n2) {
        float bv = bias[ocol0 + n2 * 16];
#pragma unroll
        for (int m2 = 0; m2 < 4; ++m2) {
#pragma unroll
            for (int r = 0; r < 4; ++r) {
                y[(size_t)(orow0 + m2 * 16 + r) * DOUT + (ocol0 + n2 * 16)]
                    = acc[m2][n2][r] + bv;
            }
        }
    }
#undef SUBSTEP
#undef LOADB
}

extern "C" void kernel_launch(void* const* d_in, const int* in_sizes, int n_in,
                              void* d_out, int out_size, void* d_ws, size_t ws_size,
                              hipStream_t stream)
{
    const float* x          = (const float*)d_in[0];
    const float* coef       = (const float*)d_in[1];
    const float* scale_base = (const float*)d_in[2];
    const float* scale_sp   = (const float*)d_in[3];
    const float* bias       = (const float*)d_in[4];
    unsigned short* wt = (unsigned short*)d_ws;   // 4 MB packed wt2[nt][kt][ks][ol][fg]
    float* y = (float*)d_out;

    kan_prep<<<1024, 256, 0, stream>>>(coef, scale_base, scale_sp, wt);
    kan_gemm<<<512, 256, 0, stream>>>(x, wt, bias, y);
}